// Round 6
// baseline (399.872 us; speedup 1.0000x reference)
//
#include <hip/hip_runtime.h>
#include <hip/hip_cooperative_groups.h>
#include <math.h>

namespace cg = cooperative_groups;

#define S_LEN 2048
#define DM 768
#define NHEAD 12
#define DHEAD 64
#define HALF_W 64

typedef _Float16 half8 __attribute__((ext_vector_type(8)));
typedef _Float16 half4_t __attribute__((ext_vector_type(4)));
typedef float floatx4 __attribute__((ext_vector_type(4)));

// ---- async global->LDS, 16B per lane (dest = wave-uniform base + lane*16) ----
typedef const __attribute__((address_space(1))) unsigned int* gas_ptr;
typedef __attribute__((address_space(3))) unsigned int* las_ptr;
__device__ __forceinline__ void gld_lds16(const void* g, void* l) {
  __builtin_amdgcn_global_load_lds((gas_ptr)g, (las_ptr)l, 16, 0, 0);
}

// ---- one LDS arena shared by all phases (max = attention: 75.6 KB) ----
union SmemU {
  struct { float t[64][65]; } p;                        // prep transpose
  struct { _Float16 As[128 * 64]; _Float16 Bs[64 * 64]; } g;  // gemm 24 KB
  struct {
    _Float16 Qs[32 * 64];     // 4 KB
    _Float16 Ks[160 * 64];    // 20 KB
    _Float16 Vs[64 * 168];    // 21 KB  (row pad 160->168: 2-way bank alias = free)
    float Sbuf[32][161];      // 20.1 KB
    _Float16 Pbuf[32][168];   // 10.5 KB
  } a;
};

// ---- 128x64 f16 MFMA GEMM tile; 4 waves 2x2, wave tile 64x32 (acc[4][2]) ----
__device__ __forceinline__ void gemm_tile(
    const _Float16* __restrict__ A, const _Float16* __restrict__ Wt,
    const float* __restrict__ bias, int m0, int n0,
    _Float16* As, _Float16* Bs, _Float16* __restrict__ Hout,
    _Float16* __restrict__ VtOut, float* __restrict__ Fout) {
  const int tid = threadIdx.x;
  const int lane = tid & 63, w = tid >> 6;
  const int lr = lane & 15, lq = lane >> 4;
  const int wm = w >> 1, wn = w & 1;
  const int wb = tid & 192;
  floatx4 acc[4][2] = {};

  for (int k0 = 0; k0 < DM; k0 += 64) {
    __syncthreads();  // protect LDS from prior iter / prior unit readers
#pragma unroll
    for (int i = 0; i < 4; ++i) {  // A: 128 rows x 8 chunks
      int c = i * 256 + tid;
      int m = c >> 3, j = c & 7, jg = j ^ (m & 7);
      gld_lds16(A + (size_t)(m0 + m) * DM + k0 + jg * 8, &As[(i * 256 + wb) * 8]);
    }
#pragma unroll
    for (int i = 0; i < 2; ++i) {  // B: 64 rows x 8 chunks
      int c = i * 256 + tid;
      int n = c >> 3, j = c & 7, jg = j ^ (n & 7);
      gld_lds16(Wt + (size_t)(n0 + n) * DM + k0 + jg * 8, &Bs[(i * 256 + wb) * 8]);
    }
    __syncthreads();  // vmcnt(0) drain -> staged data visible

#pragma unroll
    for (int kh = 0; kh < 2; ++kh) {
      half8 af[4], bf[2];
#pragma unroll
      for (int mt = 0; mt < 4; ++mt) {
        int m = wm * 64 + mt * 16 + lr;
        int j = (kh * 4 + lq) ^ (m & 7);
        af[mt] = *(const half8*)&As[m * 64 + j * 8];
      }
#pragma unroll
      for (int nt = 0; nt < 2; ++nt) {
        int n = wn * 32 + nt * 16 + lr;
        int j = (kh * 4 + lq) ^ (n & 7);
        bf[nt] = *(const half8*)&Bs[n * 64 + j * 8];
      }
#pragma unroll
      for (int mt = 0; mt < 4; ++mt)
#pragma unroll
        for (int nt = 0; nt < 2; ++nt)
          acc[mt][nt] = __builtin_amdgcn_mfma_f32_16x16x32_f16(af[mt], bf[nt], acc[mt][nt], 0, 0, 0);
    }
  }

#pragma unroll
  for (int mt = 0; mt < 4; ++mt) {
    int row0 = m0 + wm * 64 + mt * 16 + lq * 4;
#pragma unroll
    for (int nt = 0; nt < 2; ++nt) {
      int col = n0 + wn * 32 + nt * 16 + lr;
      float bv = bias[col];
      if (Fout) {
#pragma unroll
        for (int rr = 0; rr < 4; ++rr)
          Fout[(size_t)(row0 + rr) * DM + col] = acc[mt][nt][rr] + bv;
      } else if (VtOut) {  // V proj: write V^T[d=col][s=row] (fused transpose)
        half4_t o = {(_Float16)(acc[mt][nt][0] + bv), (_Float16)(acc[mt][nt][1] + bv),
                     (_Float16)(acc[mt][nt][2] + bv), (_Float16)(acc[mt][nt][3] + bv)};
        *(half4_t*)(VtOut + (size_t)col * S_LEN + row0) = o;
      } else {
#pragma unroll
        for (int rr = 0; rr < 4; ++rr)
          Hout[(size_t)(row0 + rr) * DM + col] = (_Float16)(acc[mt][nt][rr] + bv);
      }
    }
  }
}

// ---------------- the whole pipeline in one cooperative kernel ----------------
__global__ __launch_bounds__(256, 2)
void mega_kernel(const float* __restrict__ query, const float* __restrict__ key,
                 const float* __restrict__ value, const float* __restrict__ Wq,
                 const float* __restrict__ bq, const float* __restrict__ Wk,
                 const float* __restrict__ bk, const float* __restrict__ Wv,
                 const float* __restrict__ bv, const float* __restrict__ Wo,
                 const float* __restrict__ bo, float* __restrict__ out,
                 _Float16* __restrict__ ws) {
  __shared__ __align__(16) SmemU sm;
  const int tid = threadIdx.x;
  const int nblk = gridDim.x;
  const size_t nel = (size_t)S_LEN * DM;
  const size_t wel = (size_t)DM * DM;
  _Float16* Aq = ws;
  _Float16* Ak = Aq + nel;
  _Float16* Av = Ak + nel;
  _Float16* Wtq = Av + nel;
  _Float16* Wtk = Wtq + wel;
  _Float16* Wtv = Wtk + wel;
  _Float16* Wto = Wtv + wel;
  _Float16* qh = Wto + wel;
  _Float16* khb = qh + nel;
  _Float16* Vtg = khb + nel;
  _Float16* ctxh = Aq;  // Aq dead after P1
  cg::grid_group grid = cg::this_grid();

  // ================= P0: weight cvt+transpose (576) + act cvt (288) =================
  for (int u = blockIdx.x; u < 864; u += nblk) {
    if (u < 576) {
      __syncthreads();
      int z = u / 144, rem = u % 144;
      const float* W = z == 0 ? Wq : z == 1 ? Wk : z == 2 ? Wv : Wo;
      _Float16* T = z == 0 ? Wtq : z == 1 ? Wtk : z == 2 ? Wtv : Wto;
      int n0 = (rem % 12) * 64, k0 = (rem / 12) * 64;
      int tx = tid & 15, ty = tid >> 4;
#pragma unroll
      for (int i = 0; i < 4; ++i) {
        int row = ty + i * 16;
        float4 v = *(const float4*)(W + (size_t)(k0 + row) * DM + n0 + tx * 4);
        sm.p.t[row][tx * 4 + 0] = v.x; sm.p.t[row][tx * 4 + 1] = v.y;
        sm.p.t[row][tx * 4 + 2] = v.z; sm.p.t[row][tx * 4 + 3] = v.w;
      }
      __syncthreads();
#pragma unroll
      for (int i = 0; i < 4; ++i) {
        int nn = ty + i * 16, kk = tx * 4;
        half4_t h = {(_Float16)sm.p.t[kk + 0][nn], (_Float16)sm.p.t[kk + 1][nn],
                     (_Float16)sm.p.t[kk + 2][nn], (_Float16)sm.p.t[kk + 3][nn]};
        *(half4_t*)(T + (size_t)(n0 + nn) * DM + k0 + kk) = h;
      }
    } else {
      // act cvt: 288 units x 4096 float4 each, dense coverage
      // (R5 BUG was here: jj*1024 left 3/4 of each part unwritten -> 0xAA poison)
      int u2 = u - 576;
      int z = u2 / 96, part = u2 % 96;
      const float* s = z == 0 ? query : z == 1 ? key : value;
      _Float16* d = z == 0 ? Aq : z == 1 ? Ak : Av;
#pragma unroll
      for (int jj = 0; jj < 16; ++jj) {
        int idx = part * 4096 + jj * 256 + tid;
        float4 v = ((const float4*)s)[idx];
        half4_t h = {(_Float16)v.x, (_Float16)v.y, (_Float16)v.z, (_Float16)v.w};
        ((half4_t*)d)[idx] = h;
      }
    }
  }
  __threadfence(); grid.sync(); __threadfence();

  // ================= P1: QKV projections (576 tile-units) =================
  for (int u = blockIdx.x; u < 576; u += nblk) {
    int z = u / 192, rem = u % 192;
    int m0 = (rem / 12) * 128, n0 = (rem % 12) * 64;
    const _Float16* A = z == 0 ? Aq : z == 1 ? Ak : Av;
    const _Float16* Wt = z == 0 ? Wtq : z == 1 ? Wtk : Wtv;
    const float* bias = z == 0 ? bq : z == 1 ? bk : bv;
    gemm_tile(A, Wt, bias, m0, n0, sm.g.As, sm.g.Bs,
              z == 0 ? qh : khb, z == 2 ? Vtg : nullptr, nullptr);
  }
  __threadfence(); grid.sync(); __threadfence();

  // ================= P2: sliding-window attention (768 units) =================
  for (int u = blockIdx.x; u < 768; u += nblk) {
    __syncthreads();  // protect LDS from prior unit's readers
    const int s0 = (u & 63) * 32;
    const int h = u >> 6;
    const int lane = tid & 63, w = tid >> 6;
    const int lr = lane & 15, lq = lane >> 4;
    const int wb = tid & 192;

    // stage Q: 256 chunks
    {
      int r = tid >> 3, j = tid & 7;
      int jg = j ^ (r & 7);
      gld_lds16(qh + (size_t)(s0 + r) * DM + h * DHEAD + jg * 8, &sm.a.Qs[wb * 8]);
    }
    // stage K: 1280 chunks, pos clamped (masked later)
#pragma unroll
    for (int i = 0; i < 5; ++i) {
      int c = i * 256 + tid;
      int r = c >> 3, j = c & 7;
      int jg = j ^ (r & 7);
      int pos = s0 - HALF_W + r;
      pos = pos < 0 ? 0 : (pos > S_LEN - 1 ? S_LEN - 1 : pos);
      gld_lds16(khb + (size_t)pos * DM + h * DHEAD + jg * 8, &sm.a.Ks[(i * 256 + wb) * 8]);
    }
    // stage Vt: 64 rows x 21 chunks = 1344, natural layout (row pad 168)
#pragma unroll
    for (int i = 0; i < 6; ++i) {
      int c = i * 256 + tid;
      if (c < 1344) {
        int r = c / 21, j = c % 21;
        int cb = s0 - HALF_W + j * 8;
        cb = cb < 0 ? 0 : (cb > S_LEN - 8 ? S_LEN - 8 : cb);
        gld_lds16(Vtg + (size_t)(h * DHEAD + r) * S_LEN + cb, &sm.a.Vs[(i * 256 + wb) * 8]);
      }
    }
    __syncthreads();

    // QK^T: wave w -> qt=w>>1, pt in [(w&1)*5, +5)
    {
      const int qt = w >> 1;
      const int ptb = (w & 1) * 5;
      half8 aq[2];
#pragma unroll
      for (int k2 = 0; k2 < 2; ++k2) {
        int r = qt * 16 + lr, j = (k2 * 4 + lq) ^ (r & 7);
        aq[k2] = *(const half8*)&sm.a.Qs[r * DHEAD + j * 8];
      }
#pragma unroll
      for (int i = 0; i < 5; ++i) {
        int pt = ptb + i;
        floatx4 acc = {};
#pragma unroll
        for (int k2 = 0; k2 < 2; ++k2) {
          int r = pt * 16 + lr, j = (k2 * 4 + lq) ^ (r & 7);
          half8 bk2 = *(const half8*)&sm.a.Ks[r * DHEAD + j * 8];
          acc = __builtin_amdgcn_mfma_f32_16x16x32_f16(aq[k2], bk2, acc, 0, 0, 0);
        }
#pragma unroll
        for (int rr = 0; rr < 4; ++rr)
          sm.a.Sbuf[qt * 16 + lq * 4 + rr][pt * 16 + lr] = acc[rr] * 0.125f;
      }
    }
    __syncthreads();

    // masked softmax: 8 rows/wave; valid iff p-q in [0,128] && pos in [0,S)
#pragma unroll
    for (int i = 0; i < 8; ++i) {
      int q = w * 8 + i;
      int p0 = lane, p1 = 64 + lane, p2 = 128 + lane;
      int g0 = s0 - HALF_W + p0, g1 = s0 + lane, g2 = s0 + HALF_W + lane;
      bool ok0 = (p0 >= q) && (g0 >= 0);
      bool ok1 = (g1 < S_LEN);
      bool ok2 = (lane <= q) && (g2 < S_LEN);
      float sv0 = ok0 ? sm.a.Sbuf[q][p0] : -1e30f;
      float sv1 = ok1 ? sm.a.Sbuf[q][p1] : -1e30f;
      float sv2 = ok2 ? sm.a.Sbuf[q][p2] : -1e30f;
      float mx = fmaxf(sv0, fmaxf(sv1, sv2));
#pragma unroll
      for (int off = 32; off > 0; off >>= 1) mx = fmaxf(mx, __shfl_xor(mx, off, 64));
      float e0 = __expf(sv0 - mx), e1 = __expf(sv1 - mx), e2 = __expf(sv2 - mx);
      float sum = e0 + e1 + e2;
#pragma unroll
      for (int off = 32; off > 0; off >>= 1) sum += __shfl_xor(sum, off, 64);
      float inv = 1.f / sum;
      sm.a.Pbuf[q][p0] = (_Float16)(e0 * inv);
      sm.a.Pbuf[q][p1] = (_Float16)(e1 * inv);
      if (lane < 32) sm.a.Pbuf[q][p2] = (_Float16)(e2 * inv);
    }
    __syncthreads();

    // PV: wave w -> qt=w>>1, dt = (w&1)*2 + {0,1}
    {
      const int qt = w >> 1;
      const int dt0 = (w & 1) * 2;
      floatx4 a0 = {}, a1 = {};
#pragma unroll
      for (int ks = 0; ks < 5; ++ks) {
        half8 ap = *(const half8*)&sm.a.Pbuf[qt * 16 + lr][ks * 32 + lq * 8];
        half8 bv0 = *(const half8*)&sm.a.Vs[(dt0 * 16 + lr) * 168 + ks * 32 + lq * 8];
        half8 bv1 = *(const half8*)&sm.a.Vs[((dt0 + 1) * 16 + lr) * 168 + ks * 32 + lq * 8];
        a0 = __builtin_amdgcn_mfma_f32_16x16x32_f16(ap, bv0, a0, 0, 0, 0);
        a1 = __builtin_amdgcn_mfma_f32_16x16x32_f16(ap, bv1, a1, 0, 0, 0);
      }
#pragma unroll
      for (int rr = 0; rr < 4; ++rr) {
        size_t row = (size_t)(s0 + qt * 16 + lq * 4 + rr) * DM + h * DHEAD;
        ctxh[row + dt0 * 16 + lr] = (_Float16)a0[rr];
        ctxh[row + (dt0 + 1) * 16 + lr] = (_Float16)a1[rr];
      }
    }
  }
  __threadfence(); grid.sync(); __threadfence();

  // ================= P3: output projection (192 tile-units) =================
  for (int u = blockIdx.x; u < 192; u += nblk) {
    int m0 = (u / 12) * 128, n0 = (u % 12) * 64;
    gemm_tile(ctxh, Wto, bo, m0, n0, sm.g.As, sm.g.Bs, nullptr, nullptr, out);
  }
}

// ---------------- launch ----------------
extern "C" void kernel_launch(void* const* d_in, const int* in_sizes, int n_in,
                              void* d_out, int out_size, void* d_ws, size_t ws_size,
                              hipStream_t stream) {
  const float* query = (const float*)d_in[0];
  const float* key   = (const float*)d_in[1];
  const float* value = (const float*)d_in[2];
  const float* Wq = (const float*)d_in[3];
  const float* bq = (const float*)d_in[4];
  const float* Wk = (const float*)d_in[5];
  const float* bk = (const float*)d_in[6];
  const float* Wv = (const float*)d_in[7];
  const float* bv = (const float*)d_in[8];
  const float* Wo = (const float*)d_in[9];
  const float* bo = (const float*)d_in[10];
  float* out = (float*)d_out;
  _Float16* ws = (_Float16*)d_ws;

  int maxb = 0;
  hipOccupancyMaxActiveBlocksPerMultiprocessor(&maxb, (const void*)mega_kernel, 256, 0);
  if (maxb < 1) maxb = 1;
  int grid = 256 * maxb;
  if (grid > 512) grid = 512;

  void* args[] = {&query, &key, &value, &Wq, &bq, &Wk, &bk,
                  &Wv, &bv, &Wo, &bo, &out, &ws};
  hipLaunchCooperativeKernel((void*)mega_kernel, dim3(grid), dim3(256), args, 0, stream);
}

// Round 7
// 137.316 us; speedup vs baseline: 2.9121x; 2.9121x over previous
//
#include <hip/hip_runtime.h>
#include <math.h>

#define S_LEN 2048
#define DM 768
#define NHEAD 12
#define DHEAD 64
#define HALF_W 64

typedef _Float16 half8 __attribute__((ext_vector_type(8)));
typedef _Float16 half4_t __attribute__((ext_vector_type(4)));
typedef float floatx4 __attribute__((ext_vector_type(4)));

// ---- async global->LDS, 16B per lane (dest = wave-uniform base + lane*16) ----
typedef const __attribute__((address_space(1))) unsigned int* gas_ptr;
typedef __attribute__((address_space(3))) unsigned int* las_ptr;
__device__ __forceinline__ void gld_lds16(const void* g, void* l) {
  __builtin_amdgcn_global_load_lds((gas_ptr)g, (las_ptr)l, 16, 0, 0);
}

// ---------------- prep: blocks 0..575 = weight cvt+transpose; 576..5183 = act cvt ----
__global__ __launch_bounds__(256)
void prep_kernel(const float* __restrict__ Wq, const float* __restrict__ Wk,
                 const float* __restrict__ Wv, const float* __restrict__ Wo,
                 _Float16* __restrict__ Tq, _Float16* __restrict__ Tk,
                 _Float16* __restrict__ Tv, _Float16* __restrict__ To,
                 const float* __restrict__ qs, const float* __restrict__ ks,
                 const float* __restrict__ vs, _Float16* __restrict__ Aq,
                 _Float16* __restrict__ Ak, _Float16* __restrict__ Av) {
  __shared__ float t[64][65];
  int b = blockIdx.x;
  if (b < 576) {
    int z = b / 144, rem = b % 144;
    const float* W = z == 0 ? Wq : z == 1 ? Wk : z == 2 ? Wv : Wo;
    _Float16* T = z == 0 ? Tq : z == 1 ? Tk : z == 2 ? Tv : To;
    int n0 = (rem % 12) * 64, k0 = (rem / 12) * 64;
    int tx = threadIdx.x & 15, ty = threadIdx.x >> 4;
#pragma unroll
    for (int i = 0; i < 4; ++i) {
      int row = ty + i * 16;
      float4 v = *(const float4*)(W + (size_t)(k0 + row) * DM + n0 + tx * 4);
      t[row][tx * 4 + 0] = v.x; t[row][tx * 4 + 1] = v.y;
      t[row][tx * 4 + 2] = v.z; t[row][tx * 4 + 3] = v.w;
    }
    __syncthreads();
#pragma unroll
    for (int i = 0; i < 4; ++i) {
      int nn = ty + i * 16, kk = tx * 4;
      half4_t h = {(_Float16)t[kk + 0][nn], (_Float16)t[kk + 1][nn],
                   (_Float16)t[kk + 2][nn], (_Float16)t[kk + 3][nn]};
      *(half4_t*)(T + (size_t)(n0 + nn) * DM + k0 + kk) = h;
    }
  } else {
    int i = b - 576;
    int z = i / 1536;
    const float* s = z == 0 ? qs : z == 1 ? ks : vs;
    _Float16* d = z == 0 ? Aq : z == 1 ? Ak : Av;
    int idx = (i % 1536) * 256 + threadIdx.x;
    float4 v = ((const float4*)s)[idx];
    half4_t h = {(_Float16)v.x, (_Float16)v.y, (_Float16)v.z, (_Float16)v.w};
    ((half4_t*)d)[idx] = h;
  }
}

// ---------------- f16 MFMA GEMM, 64x64 block tile ----------------
// Rationale: MFMA work is ~4 us total (R6 mega counters) — the GEMMs are
// latency-bound, not pipe-bound. Small tiles maximize block count:
// QKV = 1152 blocks (4.5/CU co-resident; barrier drains overlap across blocks).
// 4 waves in 2x2, wave tile 32x32 = acc[2][2]. BK=64, XOR chunk swizzle.
#define GBM 64
#define GBN 64
#define GBK 64

__global__ __launch_bounds__(256, 4)
void gemm_f16_kernel(const _Float16* __restrict__ A0, const _Float16* __restrict__ A1,
                     const _Float16* __restrict__ A2, const _Float16* __restrict__ W0,
                     const _Float16* __restrict__ W1, const _Float16* __restrict__ W2,
                     const float* __restrict__ b0, const float* __restrict__ b1,
                     const float* __restrict__ b2, _Float16* __restrict__ H0,
                     _Float16* __restrict__ H1, _Float16* __restrict__ Vt,
                     float* __restrict__ Cf, int fp32_out) {
  __shared__ __align__(16) _Float16 As[GBM * GBK];  // 8 KB
  __shared__ __align__(16) _Float16 Bs[GBN * GBK];  // 8 KB
  const int z = blockIdx.z;
  const _Float16* A = z == 0 ? A0 : z == 1 ? A1 : A2;
  const _Float16* Wt = z == 0 ? W0 : z == 1 ? W1 : W2;
  const float* bias = z == 0 ? b0 : z == 1 ? b1 : b2;

  const int tid = threadIdx.x;
  const int lane = tid & 63;
  const int w = tid >> 6;
  const int lr = lane & 15;
  const int lq = lane >> 4;
  const int wm = w >> 1, wn = w & 1;
  const int m0 = blockIdx.y * GBM;
  const int n0 = blockIdx.x * GBN;
  const int wb = tid & 192;

  floatx4 acc[2][2] = {};

  for (int k0 = 0; k0 < DM; k0 += GBK) {
    __syncthreads();
#pragma unroll
    for (int i = 0; i < 2; ++i) {  // A: 64 rows x 8 chunks = 512
      int c = i * 256 + tid;
      int m = c >> 3, j = c & 7, jg = j ^ (m & 7);
      gld_lds16(A + (size_t)(m0 + m) * DM + k0 + jg * 8, &As[(i * 256 + wb) * 8]);
    }
#pragma unroll
    for (int i = 0; i < 2; ++i) {  // B: 64 rows x 8 chunks = 512
      int c = i * 256 + tid;
      int n = c >> 3, j = c & 7, jg = j ^ (n & 7);
      gld_lds16(Wt + (size_t)(n0 + n) * DM + k0 + jg * 8, &Bs[(i * 256 + wb) * 8]);
    }
    __syncthreads();  // vmcnt(0) drain -> staged data visible

#pragma unroll
    for (int kh = 0; kh < 2; ++kh) {
      half8 af[2], bf[2];
#pragma unroll
      for (int mt = 0; mt < 2; ++mt) {
        int m = wm * 32 + mt * 16 + lr;
        int j = (kh * 4 + lq) ^ (m & 7);
        af[mt] = *(const half8*)&As[m * GBK + j * 8];
      }
#pragma unroll
      for (int nt = 0; nt < 2; ++nt) {
        int n = wn * 32 + nt * 16 + lr;
        int j = (kh * 4 + lq) ^ (n & 7);
        bf[nt] = *(const half8*)&Bs[n * GBK + j * 8];
      }
#pragma unroll
      for (int mt = 0; mt < 2; ++mt)
#pragma unroll
        for (int nt = 0; nt < 2; ++nt)
          acc[mt][nt] = __builtin_amdgcn_mfma_f32_16x16x32_f16(af[mt], bf[nt], acc[mt][nt], 0, 0, 0);
    }
  }

#pragma unroll
  for (int mt = 0; mt < 2; ++mt) {
    int row0 = m0 + wm * 32 + mt * 16 + lq * 4;
#pragma unroll
    for (int nt = 0; nt < 2; ++nt) {
      int col = n0 + wn * 32 + nt * 16 + lr;
      float bv = bias[col];
      if (fp32_out) {
#pragma unroll
        for (int rr = 0; rr < 4; ++rr)
          Cf[(size_t)(row0 + rr) * DM + col] = acc[mt][nt][rr] + bv;
      } else if (z == 2) {  // V proj: write V^T[d=col][s=row] (fused transpose)
        half4_t o = {(_Float16)(acc[mt][nt][0] + bv), (_Float16)(acc[mt][nt][1] + bv),
                     (_Float16)(acc[mt][nt][2] + bv), (_Float16)(acc[mt][nt][3] + bv)};
        *(half4_t*)(Vt + (size_t)col * S_LEN + row0) = o;
      } else {
        _Float16* H = z == 0 ? H0 : H1;
#pragma unroll
        for (int rr = 0; rr < 4; ++rr)
          H[(size_t)(row0 + rr) * DM + col] = (_Float16)(acc[mt][nt][rr] + bv);
      }
    }
  }
}

// ---------------- MFMA sliding-window attention (unchanged from R4) ----------------
#define ATQ 32
#define AR 160
#define VTC 24

__global__ __launch_bounds__(256, 2)
void swattn_mfma_kernel(const _Float16* __restrict__ qh, const _Float16* __restrict__ kh,
                        const _Float16* __restrict__ vt, _Float16* __restrict__ ctx) {
  __shared__ __align__(16) _Float16 Qs[ATQ * DHEAD];       // 4 KB
  __shared__ __align__(16) _Float16 Ks[AR * DHEAD];        // 20 KB
  __shared__ __align__(16) _Float16 Vs[DHEAD * VTC * 8];   // 24 KB
  __shared__ float Sbuf[ATQ][161];                         // 20.1 KB
  __shared__ __align__(16) _Float16 Pbuf[ATQ][168];        // 10.5 KB

  const int tid = threadIdx.x;
  const int lane = tid & 63, w = tid >> 6;
  const int lr = lane & 15, lq = lane >> 4;
  const int s0 = blockIdx.x * ATQ;
  const int h = blockIdx.y;
  const int wb = tid & 192;

  {
    int r = tid >> 3, j = tid & 7;
    int jg = j ^ (r & 7);
    gld_lds16(qh + (size_t)(s0 + r) * DM + h * DHEAD + jg * 8, &Qs[wb * 8]);
  }
#pragma unroll
  for (int i = 0; i < 5; ++i) {
    int c = i * 256 + tid;
    int r = c >> 3, j = c & 7;
    int jg = j ^ (r & 7);
    int pos = s0 - HALF_W + r;
    pos = pos < 0 ? 0 : (pos > S_LEN - 1 ? S_LEN - 1 : pos);
    gld_lds16(kh + (size_t)pos * DM + h * DHEAD + jg * 8, &Ks[(i * 256 + wb) * 8]);
  }
#pragma unroll
  for (int i = 0; i < 6; ++i) {
    int c = i * 256 + tid;
    if (c < 1536) {
      int r = c / VTC, j = c % VTC;
      int jg = j ^ (r & 7);
      int cb = s0 - HALF_W + jg * 8;
      cb = cb < 0 ? 0 : (cb > S_LEN - 8 ? S_LEN - 8 : cb);
      gld_lds16(vt + (size_t)(h * DHEAD + r) * S_LEN + cb, &Vs[(i * 256 + wb) * 8]);
    }
  }
  __syncthreads();

  {
    const int qt = w >> 1;
    const int ptb = (w & 1) * 5;
    half8 aq[2];
#pragma unroll
    for (int k2 = 0; k2 < 2; ++k2) {
      int r = qt * 16 + lr, j = (k2 * 4 + lq) ^ (r & 7);
      aq[k2] = *(const half8*)&Qs[r * DHEAD + j * 8];
    }
#pragma unroll
    for (int i = 0; i < 5; ++i) {
      int pt = ptb + i;
      floatx4 acc = {};
#pragma unroll
      for (int k2 = 0; k2 < 2; ++k2) {
        int r = pt * 16 + lr, j = (k2 * 4 + lq) ^ (r & 7);
        half8 bk2 = *(const half8*)&Ks[r * DHEAD + j * 8];
        acc = __builtin_amdgcn_mfma_f32_16x16x32_f16(aq[k2], bk2, acc, 0, 0, 0);
      }
#pragma unroll
      for (int rr = 0; rr < 4; ++rr)
        Sbuf[qt * 16 + lq * 4 + rr][pt * 16 + lr] = acc[rr] * 0.125f;
    }
  }
  __syncthreads();

#pragma unroll
  for (int i = 0; i < 8; ++i) {
    int q = w * 8 + i;
    int p0 = lane, p1 = 64 + lane, p2 = 128 + lane;
    int g0 = s0 - HALF_W + p0, g1 = s0 + lane, g2 = s0 + HALF_W + lane;
    bool ok0 = (p0 >= q) && (g0 >= 0);
    bool ok1 = (g1 < S_LEN);
    bool ok2 = (lane <= q) && (g2 < S_LEN);
    float sv0 = ok0 ? Sbuf[q][p0] : -1e30f;
    float sv1 = ok1 ? Sbuf[q][p1] : -1e30f;
    float sv2 = ok2 ? Sbuf[q][p2] : -1e30f;
    float mx = fmaxf(sv0, fmaxf(sv1, sv2));
#pragma unroll
    for (int off = 32; off > 0; off >>= 1) mx = fmaxf(mx, __shfl_xor(mx, off, 64));
    float e0 = __expf(sv0 - mx), e1 = __expf(sv1 - mx), e2 = __expf(sv2 - mx);
    float sum = e0 + e1 + e2;
#pragma unroll
    for (int off = 32; off > 0; off >>= 1) sum += __shfl_xor(sum, off, 64);
    float inv = 1.f / sum;
    Pbuf[q][p0] = (_Float16)(e0 * inv);
    Pbuf[q][p1] = (_Float16)(e1 * inv);
    if (lane < 32) Pbuf[q][p2] = (_Float16)(e2 * inv);
  }
  __syncthreads();

  {
    const int qt = w >> 1;
    const int dt0 = (w & 1) * 2;
    floatx4 a0 = {}, a1 = {};
#pragma unroll
    for (int ks = 0; ks < 5; ++ks) {
      half8 ap = *(const half8*)&Pbuf[qt * 16 + lr][ks * 32 + lq * 8];
      int r0 = dt0 * 16 + lr, r1 = (dt0 + 1) * 16 + lr;
      int j0 = (ks * 4 + lq) ^ (r0 & 7), j1 = (ks * 4 + lq) ^ (r1 & 7);
      half8 bv0 = *(const half8*)&Vs[(r0 * VTC + j0) * 8];
      half8 bv1 = *(const half8*)&Vs[(r1 * VTC + j1) * 8];
      a0 = __builtin_amdgcn_mfma_f32_16x16x32_f16(ap, bv0, a0, 0, 0, 0);
      a1 = __builtin_amdgcn_mfma_f32_16x16x32_f16(ap, bv1, a1, 0, 0, 0);
    }
#pragma unroll
    for (int rr = 0; rr < 4; ++rr) {
      size_t row = (size_t)(s0 + qt * 16 + lq * 4 + rr) * DM + h * DHEAD;
      ctx[row + dt0 * 16 + lr] = (_Float16)a0[rr];
      ctx[row + (dt0 + 1) * 16 + lr] = (_Float16)a1[rr];
    }
  }
}

// ---------------- launch ----------------
extern "C" void kernel_launch(void* const* d_in, const int* in_sizes, int n_in,
                              void* d_out, int out_size, void* d_ws, size_t ws_size,
                              hipStream_t stream) {
  const float* query = (const float*)d_in[0];
  const float* key   = (const float*)d_in[1];
  const float* value = (const float*)d_in[2];
  const float* Wq = (const float*)d_in[3];
  const float* bq = (const float*)d_in[4];
  const float* Wk = (const float*)d_in[5];
  const float* bk = (const float*)d_in[6];
  const float* Wv = (const float*)d_in[7];
  const float* bv = (const float*)d_in[8];
  const float* Wo = (const float*)d_in[9];
  const float* bo = (const float*)d_in[10];
  float* out = (float*)d_out;

  const size_t nel = (size_t)S_LEN * DM;
  const size_t wel = (size_t)DM * DM;
  _Float16* Aq = (_Float16*)d_ws;
  _Float16* Ak = Aq + nel;
  _Float16* Av = Ak + nel;
  _Float16* Wtq = Av + nel;
  _Float16* Wtk = Wtq + wel;
  _Float16* Wtv = Wtk + wel;
  _Float16* Wto = Wtv + wel;
  _Float16* qh = Wto + wel;
  _Float16* khb = qh + nel;
  _Float16* Vtg = khb + nel;  // [768][2048] f16 (do NOT alias A*)
  _Float16* ctxh = Aq;        // Aq dead after QKV GEMM

  prep_kernel<<<dim3(576 + 4608), 256, 0, stream>>>(
      Wq, Wk, Wv, Wo, Wtq, Wtk, Wtv, Wto, query, key, value, Aq, Ak, Av);
  gemm_f16_kernel<<<dim3(DM / GBN, S_LEN / GBM, 3), 256, 0, stream>>>(
      Aq, Ak, Av, Wtq, Wtk, Wtv, bq, bk, bv, qh, khb, Vtg, nullptr, 0);
  swattn_mfma_kernel<<<dim3(S_LEN / ATQ, NHEAD), 256, 0, stream>>>(qh, khb, Vtg, ctxh);
  gemm_f16_kernel<<<dim3(DM / GBN, S_LEN / GBM, 1), 256, 0, stream>>>(
      ctxh, ctxh, ctxh, Wto, Wto, Wto, bo, bo, bo, nullptr, nullptr, nullptr, out, 1);
}